// Round 1
// baseline (1735.354 us; speedup 1.0000x reference)
//
#include <hip/hip_runtime.h>
#include <math.h>

#define B_ 4
#define N_ 4096
#define C_ 1024
#define H_ 16
#define D_ 64
#define M_ (B_*N_)      // 16384 rows
#define K_ C_           // 1024
#define TC_ (3*C_)      // 3072

#define TILE 128
#define BK 16
#define LDSP 132        // padded LDS leading dim for GEMM tiles
#define NCH 8           // N-chunks for kv partial reduction
#define CHROWS (N_/NCH) // 512

__device__ __forceinline__ float phi_f(float t) {
  return (t > 0.0f) ? (t + 1.0f) : __expf(t);
}

// ---------------- mask dtype detection ----------------
// flag: 0 = int32 {0,1}, 1 = float32 {0.0,1.0}, 2 = bytes (uint8/int8 bool)
__global__ __launch_bounds__(256) void mask_detect_k(const unsigned int* __restrict__ w,
                                                     int* __restrict__ flag) {
  __shared__ int notint, notflt;
  if (threadIdx.x == 0) { notint = 0; notflt = 0; }
  __syncthreads();
  int ni = 0, nf = 0;
  // first 4096 words are safe to read under every candidate layout
  for (int i = threadIdx.x; i < 4096; i += 256) {
    unsigned int v = w[i];
    if (v > 1u) ni = 1;
    if (v != 0u && v != 0x3F800000u) nf = 1;
  }
  if (ni) atomicOr(&notint, 1);
  if (nf) atomicOr(&notflt, 1);
  __syncthreads();
  if (threadIdx.x == 0) *flag = (!notint) ? 0 : ((!notflt) ? 1 : 2);
}

__global__ __launch_bounds__(256) void mask_convert_k(const void* __restrict__ mask,
                                                      const int* __restrict__ flag,
                                                      float* __restrict__ valid) {
  int i = blockIdx.x * 256 + threadIdx.x;  // 16384 total
  int f = *flag;
  int m;
  if (f == 0)      m = ((const int*)mask)[i] != 0;
  else if (f == 1) m = ((const float*)mask)[i] != 0.0f;
  else             m = ((const unsigned char*)mask)[i] != 0;
  valid[i] = m ? 0.0f : 1.0f;  // True = PAD -> 0
}

// ---------------- QKV GEMM: out[m][j] = sum_k X[m][k]*W[j][k] + b[j], fused phi/mask ----------------
__global__ __launch_bounds__(256) void gemm_qkv_k(
    const float* __restrict__ X, const float* __restrict__ W,
    const float* __restrict__ bias, const float* __restrict__ valid,
    float* __restrict__ qf, float* __restrict__ kf, float* __restrict__ vv) {
  __shared__ float As[BK][LDSP];
  __shared__ float Bs[BK][LDSP];
  const int m0 = blockIdx.x * TILE;
  const int j0 = blockIdx.y * TILE;
  const int tid = threadIdx.x;
  const int tx = tid & 15, ty = tid >> 4;
  const int lq = tid & 3;      // which float4 of the 16-float row chunk
  const int lr = tid >> 2;     // row 0..63
  float acc[8][8] = {};
  for (int k0 = 0; k0 < K_; k0 += BK) {
#pragma unroll
    for (int hh = 0; hh < 2; ++hh) {
      int mm = lr + 64 * hh;
      float4 a = *(const float4*)&X[(size_t)(m0 + mm) * K_ + k0 + lq * 4];
      As[lq*4+0][mm] = a.x; As[lq*4+1][mm] = a.y; As[lq*4+2][mm] = a.z; As[lq*4+3][mm] = a.w;
      float4 b = *(const float4*)&W[(size_t)(j0 + mm) * K_ + k0 + lq * 4];
      Bs[lq*4+0][mm] = b.x; Bs[lq*4+1][mm] = b.y; Bs[lq*4+2][mm] = b.z; Bs[lq*4+3][mm] = b.w;
    }
    __syncthreads();
#pragma unroll
    for (int k = 0; k < BK; ++k) {
      float a[8], bb[8];
      *(float4*)&a[0]  = *(const float4*)&As[k][ty * 4];
      *(float4*)&a[4]  = *(const float4*)&As[k][ty * 4 + 64];
      *(float4*)&bb[0] = *(const float4*)&Bs[k][tx * 4];
      *(float4*)&bb[4] = *(const float4*)&Bs[k][tx * 4 + 64];
#pragma unroll
      for (int i = 0; i < 8; ++i)
#pragma unroll
        for (int j = 0; j < 8; ++j) acc[i][j] += a[i] * bb[j];
    }
    __syncthreads();
  }
  // epilogue: tensor t uniform per block (1024 % TILE == 0)
  const int t = j0 >> 10;
  float* dst = (t == 0) ? qf : ((t == 1) ? kf : vv);
#pragma unroll
  for (int i = 0; i < 8; ++i) {
    int m = m0 + (ty << 2) + (i & 3) + ((i >> 2) << 6);
    int b = m >> 12, n = m & 4095;
    float vld = valid[m];
#pragma unroll
    for (int jj = 0; jj < 2; ++jj) {
      int jcol = j0 + (tx << 2) + (jj << 6);
      int c = jcol & 1023;
      int h = c >> 6, d = c & 63;
      float tmp[4];
#pragma unroll
      for (int q = 0; q < 4; ++q) {
        float val = acc[i][(jj << 2) + q] + bias[jcol + q];
        if (t == 0)      val = phi_f(val);
        else if (t == 1) val = phi_f(val) * vld;
        else             val = val * vld;
        tmp[q] = val;
      }
      float4 r = make_float4(tmp[0], tmp[1], tmp[2], tmp[3]);
      size_t o = (((size_t)(b * H_ + h) * N_ + n) << 6) + d;
      *(float4*)&dst[o] = r;
    }
  }
}

// ---------------- kv partials: kv[bh][d][e] = sum_n kf[bh][n][d]*v[bh][n][e]; z[bh][d] ----------------
__global__ __launch_bounds__(256) void kv_partial_k(
    const float* __restrict__ kf, const float* __restrict__ vv,
    float* __restrict__ kvp, float* __restrict__ zp) {
  const int bh = blockIdx.x, ch = blockIdx.y;
  const float* kfr = kf + ((size_t)bh * N_ + ch * CHROWS) * 64;
  const float* vr  = vv + ((size_t)bh * N_ + ch * CHROWS) * 64;
  __shared__ float ks[8][64], vs[8][64];
  const int tid = threadIdx.x;
  const int d0 = tid >> 2, eg = tid & 3;
  float acc[16] = {};
  float zacc = 0.f;
  for (int nb = 0; nb < CHROWS; nb += 8) {
    {
      int which = tid >> 7;           // 0: kf, 1: v
      int fl = tid & 127;             // float4 idx: row = fl>>4, col4 = (fl&15)*4
      int rr = fl >> 4, cc = (fl & 15) * 4;
      const float* src = which ? vr : kfr;
      float4 t4 = *(const float4*)&src[(size_t)(nb + rr) * 64 + cc];
      float* d = which ? &vs[rr][cc] : &ks[rr][cc];
      *(float4*)d = t4;
    }
    __syncthreads();
#pragma unroll
    for (int r = 0; r < 8; ++r) {
      float kd = ks[r][d0];
      if (eg == 0) zacc += kd;
#pragma unroll
      for (int i = 0; i < 16; ++i) acc[i] += kd * vs[r][eg * 16 + i];
    }
    __syncthreads();
  }
  size_t base = ((size_t)bh * NCH + ch) * 4096 + (size_t)d0 * 64 + eg * 16;
#pragma unroll
  for (int i = 0; i < 16; i += 4)
    *(float4*)&kvp[base + i] = make_float4(acc[i], acc[i+1], acc[i+2], acc[i+3]);
  if (eg == 0) zp[((size_t)bh * NCH + ch) * 64 + d0] = zacc;
}

__global__ __launch_bounds__(256) void kv_reduce_k(
    const float* __restrict__ kvp, const float* __restrict__ zp,
    float* __restrict__ kv, float* __restrict__ z) {
  const int bh = blockIdx.x, tid = threadIdx.x;
  for (int i = tid; i < 4096; i += 256) {
    float s = 0.f;
#pragma unroll
    for (int c = 0; c < NCH; ++c) s += kvp[((size_t)bh * NCH + c) * 4096 + i];
    kv[(size_t)bh * 4096 + i] = s;
  }
  if (tid < 64) {
    float s = 0.f;
#pragma unroll
    for (int c = 0; c < NCH; ++c) s += zp[((size_t)bh * NCH + c) * 64 + tid];
    z[bh * 64 + tid] = s;
  }
}

// ---------------- apply: y[b,n,h*64+e] = (qf . kv) / max(qf . z, eps) ----------------
__global__ __launch_bounds__(256) void attn_apply_k(
    const float* __restrict__ qf, const float* __restrict__ kv,
    const float* __restrict__ z, float* __restrict__ y) {
  const int bh = blockIdx.x, nt = blockIdx.y;
  const int b = bh >> 4, h = bh & 15;
  __shared__ float qs[128][65];
  __shared__ float kvs[64][68];
  __shared__ float zs[64];
  __shared__ float dens[128];
  const int tid = threadIdx.x;
  const float* qrow = qf + ((size_t)bh * N_ + nt * 128) * 64;
#pragma unroll
  for (int i = 0; i < 4; ++i) {
    int fl = tid + i * 256;            // 0..1023
    int d = fl >> 4, cc = (fl & 15) * 4;
    float4 t4 = *(const float4*)&kv[(size_t)bh * 4096 + d * 64 + cc];
    kvs[d][cc] = t4.x; kvs[d][cc+1] = t4.y; kvs[d][cc+2] = t4.z; kvs[d][cc+3] = t4.w;
  }
  if (tid < 64) zs[tid] = z[bh * 64 + tid];
#pragma unroll
  for (int i = 0; i < 8; ++i) {
    int fl = tid + i * 256;            // 0..2047
    int r = fl >> 4, cc = (fl & 15) * 4;
    float4 t4 = *(const float4*)&qrow[(size_t)r * 64 + cc];
    qs[r][cc] = t4.x; qs[r][cc+1] = t4.y; qs[r][cc+2] = t4.z; qs[r][cc+3] = t4.w;
  }
  __syncthreads();
  {
    int n = tid >> 1, half = tid & 1;
    float s = 0.f;
#pragma unroll
    for (int dd = 0; dd < 32; ++dd) {
      int d = half * 32 + dd;
      s += qs[n][d] * zs[d];
    }
    float other = __shfl_down(s, 1);
    if (half == 0) dens[n] = fmaxf(s + other, 1e-6f);
  }
  __syncthreads();
  const int ng = tid >> 3, eg = tid & 7;   // 32 n-groups x 8 e-groups
  float acc[4][8] = {};
  for (int d = 0; d < 64; ++d) {
    float kvrow[8];
    *(float4*)&kvrow[0] = *(const float4*)&kvs[d][eg * 8];
    *(float4*)&kvrow[4] = *(const float4*)&kvs[d][eg * 8 + 4];
#pragma unroll
    for (int i = 0; i < 4; ++i) {
      float a = qs[ng * 4 + i][d];
#pragma unroll
      for (int j = 0; j < 8; ++j) acc[i][j] += a * kvrow[j];
    }
  }
#pragma unroll
  for (int i = 0; i < 4; ++i) {
    int nl = ng * 4 + i;
    int n = nt * 128 + nl;
    float inv = 1.0f / dens[nl];
    float* dst = y + ((size_t)b * N_ + n) * C_ + h * 64 + eg * 8;
    *(float4*)&dst[0] = make_float4(acc[i][0]*inv, acc[i][1]*inv, acc[i][2]*inv, acc[i][3]*inv);
    *(float4*)&dst[4] = make_float4(acc[i][4]*inv, acc[i][5]*inv, acc[i][6]*inv, acc[i][7]*inv);
  }
}

// ---------------- out GEMM: out[m][j] = sum_c Y[m][c]*W[j][c] + b[j] ----------------
__global__ __launch_bounds__(256) void gemm_out_k(
    const float* __restrict__ Y, const float* __restrict__ W,
    const float* __restrict__ bias, float* __restrict__ out) {
  __shared__ float As[BK][LDSP];
  __shared__ float Bs[BK][LDSP];
  const int m0 = blockIdx.x * TILE;
  const int j0 = blockIdx.y * TILE;
  const int tid = threadIdx.x;
  const int tx = tid & 15, ty = tid >> 4;
  const int lq = tid & 3;
  const int lr = tid >> 2;
  float acc[8][8] = {};
  for (int k0 = 0; k0 < K_; k0 += BK) {
#pragma unroll
    for (int hh = 0; hh < 2; ++hh) {
      int mm = lr + 64 * hh;
      float4 a = *(const float4*)&Y[(size_t)(m0 + mm) * K_ + k0 + lq * 4];
      As[lq*4+0][mm] = a.x; As[lq*4+1][mm] = a.y; As[lq*4+2][mm] = a.z; As[lq*4+3][mm] = a.w;
      float4 b = *(const float4*)&W[(size_t)(j0 + mm) * K_ + k0 + lq * 4];
      Bs[lq*4+0][mm] = b.x; Bs[lq*4+1][mm] = b.y; Bs[lq*4+2][mm] = b.z; Bs[lq*4+3][mm] = b.w;
    }
    __syncthreads();
#pragma unroll
    for (int k = 0; k < BK; ++k) {
      float a[8], bb[8];
      *(float4*)&a[0]  = *(const float4*)&As[k][ty * 4];
      *(float4*)&a[4]  = *(const float4*)&As[k][ty * 4 + 64];
      *(float4*)&bb[0] = *(const float4*)&Bs[k][tx * 4];
      *(float4*)&bb[4] = *(const float4*)&Bs[k][tx * 4 + 64];
#pragma unroll
      for (int i = 0; i < 8; ++i)
#pragma unroll
        for (int j = 0; j < 8; ++j) acc[i][j] += a[i] * bb[j];
    }
    __syncthreads();
  }
#pragma unroll
  for (int i = 0; i < 8; ++i) {
    int m = m0 + (ty << 2) + (i & 3) + ((i >> 2) << 6);
#pragma unroll
    for (int jj = 0; jj < 2; ++jj) {
      int jcol = j0 + (tx << 2) + (jj << 6);
      float4 r = make_float4(acc[i][(jj<<2)+0] + bias[jcol+0],
                             acc[i][(jj<<2)+1] + bias[jcol+1],
                             acc[i][(jj<<2)+2] + bias[jcol+2],
                             acc[i][(jj<<2)+3] + bias[jcol+3]);
      *(float4*)&out[(size_t)m * C_ + jcol] = r;
    }
  }
}

extern "C" void kernel_launch(void* const* d_in, const int* in_sizes, int n_in,
                              void* d_out, int out_size, void* d_ws, size_t ws_size,
                              hipStream_t stream) {
  const float* x      = (const float*)d_in[0];
  const float* W_qkv  = (const float*)d_in[1];
  const float* b_qkv  = (const float*)d_in[2];
  const float* W_out  = (const float*)d_in[3];
  const float* b_out  = (const float*)d_in[4];
  const void*  mask   = d_in[5];
  float* out = (float*)d_out;
  float* ws = (float*)d_ws;

  const size_t bhnd = (size_t)B_ * H_ * N_ * D_;   // 16,777,216
  size_t off_qf = 0;
  size_t off_kf = off_qf + bhnd;
  size_t off_v  = off_kf + bhnd;
  size_t off_kvp = off_v + bhnd;                    // 64*8*4096
  size_t off_zp  = off_kvp + (size_t)64 * NCH * 4096;
  size_t off_kv  = off_zp + (size_t)64 * NCH * 64;
  size_t off_z   = off_kv + (size_t)64 * 4096;
  size_t off_valid = off_z + 64 * 64;
  size_t off_flag  = off_valid + M_;

  float* qf = ws + off_qf;
  float* kf = ws + off_kf;
  float* vv = ws + off_v;
  float* kvp = ws + off_kvp;
  float* zp  = ws + off_zp;
  float* kv  = ws + off_kv;
  float* z   = ws + off_z;
  float* valid = ws + off_valid;
  int* flag = (int*)(ws + off_flag);
  float* y = kf;  // alias: kf is dead after kv_partial_k

  mask_detect_k<<<1, 256, 0, stream>>>((const unsigned int*)mask, flag);
  mask_convert_k<<<M_ / 256, 256, 0, stream>>>(mask, flag, valid);
  gemm_qkv_k<<<dim3(M_ / TILE, TC_ / TILE), 256, 0, stream>>>(x, W_qkv, b_qkv, valid, qf, kf, vv);
  kv_partial_k<<<dim3(B_ * H_, NCH), 256, 0, stream>>>(kf, vv, kvp, zp);
  kv_reduce_k<<<B_ * H_, 256, 0, stream>>>(kvp, zp, kv, z);
  attn_apply_k<<<dim3(B_ * H_, N_ / 128), 256, 0, stream>>>(qf, kv, z, y);
  gemm_out_k<<<dim3(M_ / TILE, C_ / TILE), 256, 0, stream>>>(y, W_out, b_out, out);
}

// Round 3
// 744.376 us; speedup vs baseline: 2.3313x; 2.3313x over previous
//
#include <hip/hip_runtime.h>
#include <math.h>

#define B_ 4
#define N_ 4096
#define C_ 1024
#define H_ 16
#define D_ 64
#define M_ (B_*N_)      // 16384 rows
#define GK 1024         // GEMM K dim (both GEMMs)
#define NCH 8           // N-chunks for kv partial reduction
#define CHROWS (N_/NCH) // 512

typedef __attribute__((ext_vector_type(8))) short short8;
typedef __attribute__((ext_vector_type(4))) short short4v;
typedef __attribute__((ext_vector_type(4))) float f32x4;

__device__ __forceinline__ float phi_f(float t) {
  return (t > 0.0f) ? (t + 1.0f) : __expf(t);
}

// round-to-nearest-even bf16 split: v = hi + lo to ~17 mantissa bits
__device__ __forceinline__ void split_bf16(float v, short& h, short& l) {
  unsigned u = __float_as_uint(v);
  unsigned hb = (u + 0x7FFFu + ((u >> 16) & 1u)) & 0xFFFF0000u;
  h = (short)(hb >> 16);
  float r = v - __uint_as_float(hb);
  unsigned ul = __float_as_uint(r);
  l = (short)((ul + 0x7FFFu + ((ul >> 16) & 1u)) >> 16);
}

#define GLOAD(gp, lp) __builtin_amdgcn_global_load_lds( \
    (const __attribute__((address_space(1))) unsigned int*)(gp), \
    (__attribute__((address_space(3))) unsigned int*)(lp), 16, 0, 0)

__device__ __forceinline__ f32x4 mfma16(short8 a, short8 b, f32x4 c) {
  return __builtin_amdgcn_mfma_f32_16x16x32_bf16(a, b, c, 0, 0, 0);
}

// ---------------- mask dtype detection ----------------
__global__ __launch_bounds__(256) void mask_detect_k(const unsigned int* __restrict__ w,
                                                     int* __restrict__ flag) {
  __shared__ int notint, notflt;
  if (threadIdx.x == 0) { notint = 0; notflt = 0; }
  __syncthreads();
  int ni = 0, nf = 0;
  for (int i = threadIdx.x; i < 4096; i += 256) {
    unsigned int v = w[i];
    if (v > 1u) ni = 1;
    if (v != 0u && v != 0x3F800000u) nf = 1;
  }
  if (ni) atomicOr(&notint, 1);
  if (nf) atomicOr(&notflt, 1);
  __syncthreads();
  if (threadIdx.x == 0) *flag = (!notint) ? 0 : ((!notflt) ? 1 : 2);
}

__global__ __launch_bounds__(256) void mask_convert_k(const void* __restrict__ mask,
                                                      const int* __restrict__ flag,
                                                      float* __restrict__ valid) {
  int i = blockIdx.x * 256 + threadIdx.x;  // 16384 total
  int f = *flag;
  int m;
  if (f == 0)      m = ((const int*)mask)[i] != 0;
  else if (f == 1) m = ((const float*)mask)[i] != 0.0f;
  else             m = ((const unsigned char*)mask)[i] != 0;
  valid[i] = m ? 0.0f : 1.0f;  // True = PAD -> 0
}

// ---------------- fp32 -> bf16 hi/lo split (vectorized x4) ----------------
__global__ __launch_bounds__(256) void split_f32_k(const float* __restrict__ src,
                                                   short* __restrict__ h,
                                                   short* __restrict__ l, int n4) {
  int i = blockIdx.x * 256 + threadIdx.x;
  if (i >= n4) return;
  float4 v = ((const float4*)src)[i];
  short4v hv, lv;
  short th, tl;
  split_bf16(v.x, th, tl); hv[0] = th; lv[0] = tl;
  split_bf16(v.y, th, tl); hv[1] = th; lv[1] = tl;
  split_bf16(v.z, th, tl); hv[2] = th; lv[2] = tl;
  split_bf16(v.w, th, tl); hv[3] = th; lv[3] = tl;
  ((short4v*)h)[i] = hv;
  ((short4v*)l)[i] = lv;
}

// ---------------- split-3 bf16 MFMA GEMM: out[m][j] = sum_k A[m][k]*B[j][k] ----------------
// 128x128 tile, BK=32, 4 waves (2x2), per-wave 4x4 of 16x16x32 MFMA.
// LDS in fragment order: subtile s (16 rows x 32 k) = 1024B, lane L holds
// row (L&15), k (L>>4)*8..+8  ->  global_load_lds dest lane*16B matches exactly.
// EPI 0: qkv epilogue (bias + phi/mask, scatter to [B,H,N,D]); EPI 1: bias + row-major out.
template <int EPI>
__global__ __launch_bounds__(256) void gemm_split3_k(
    const short* __restrict__ Ah, const short* __restrict__ Al,
    const short* __restrict__ Bh, const short* __restrict__ Bl,
    const float* __restrict__ bias, const float* __restrict__ valid,
    float* __restrict__ qf, float* __restrict__ kf, float* __restrict__ vv,
    float* __restrict__ outp, int jb) {
  __shared__ short lAh[4096], lAl[4096], lBh[4096], lBl[4096];  // 8KB each
  const int tid = threadIdx.x;
  const int lane = tid & 63, w = tid >> 6;
  const int lm = lane & 15, lq = lane >> 4;
  const int wm = w >> 1, wj = w & 1;
  const int m0 = blockIdx.x * 128;
  const int jg0 = jb + blockIdx.y * 128;
  const int colk = lq * 8;
  const size_t rA0 = (size_t)(m0 + w * 16 + lm) * GK + colk;
  const size_t rA1 = rA0 + (size_t)64 * GK;
  const size_t rB0 = (size_t)(jg0 + w * 16 + lm) * GK + colk;
  const size_t rB1 = rB0 + (size_t)64 * GK;
  short* dA0 = lAh + w * 512;  short* dA1 = lAh + (w + 4) * 512;
  short* dB0 = lBh + w * 512;  short* dB1 = lBh + (w + 4) * 512;
  short* eA0 = lAl + w * 512;  short* eA1 = lAl + (w + 4) * 512;
  short* eB0 = lBl + w * 512;  short* eB1 = lBl + (w + 4) * 512;

  f32x4 acc[4][4] = {};
  for (int k0 = 0; k0 < GK; k0 += 32) {
    GLOAD(Ah + rA0 + k0, dA0);
    GLOAD(Ah + rA1 + k0, dA1);
    GLOAD(Al + rA0 + k0, eA0);
    GLOAD(Al + rA1 + k0, eA1);
    GLOAD(Bh + rB0 + k0, dB0);
    GLOAD(Bh + rB1 + k0, dB1);
    GLOAD(Bl + rB0 + k0, eB0);
    GLOAD(Bl + rB1 + k0, eB1);
    __syncthreads();
    short8 a_h[4], a_l[4], b_h[4], b_l[4];
#pragma unroll
    for (int i = 0; i < 4; ++i) {
      a_h[i] = *(const short8*)&lAh[(wm * 4 + i) * 512 + lane * 8];
      a_l[i] = *(const short8*)&lAl[(wm * 4 + i) * 512 + lane * 8];
      b_h[i] = *(const short8*)&lBh[(wj * 4 + i) * 512 + lane * 8];
      b_l[i] = *(const short8*)&lBl[(wj * 4 + i) * 512 + lane * 8];
    }
#pragma unroll
    for (int i = 0; i < 4; ++i)
#pragma unroll
      for (int j = 0; j < 4; ++j) {
        acc[i][j] = mfma16(a_h[i], b_h[j], acc[i][j]);
        acc[i][j] = mfma16(a_l[i], b_h[j], acc[i][j]);
        acc[i][j] = mfma16(a_h[i], b_l[j], acc[i][j]);
      }
    __syncthreads();
  }

  // C/D layout: col = lane&15, row = (lane>>4)*4 + reg   [m89-verified]
  if (EPI == 0) {
    const int t = jg0 >> 10;  // 0:q 1:k 2:v  (uniform per block: 128 | 1024)
    float* dst = (t == 0) ? qf : ((t == 1) ? kf : vv);
    float vld[4][4];
#pragma unroll
    for (int i = 0; i < 4; ++i)
#pragma unroll
      for (int r = 0; r < 4; ++r)
        vld[i][r] = (t == 0) ? 1.0f : valid[m0 + wm * 64 + i * 16 + lq * 4 + r];
#pragma unroll
    for (int jt = 0; jt < 4; ++jt) {
      int jcol = jg0 + wj * 64 + jt * 16 + lm;
      float bj = bias[jcol];
      int c = jcol & 1023, hd = c >> 6, d = c & 63;
#pragma unroll
      for (int i = 0; i < 4; ++i)
#pragma unroll
        for (int r = 0; r < 4; ++r) {
          int m = m0 + wm * 64 + i * 16 + lq * 4 + r;
          int b = m >> 12, n = m & 4095;
          float val = acc[i][jt][r] + bj;
          if (t <= 1) val = phi_f(val);
          if (t >= 1) val *= vld[i][r];
          dst[(((size_t)(b * H_ + hd) * N_ + n) << 6) + d] = val;
        }
    }
  } else {
#pragma unroll
    for (int jt = 0; jt < 4; ++jt) {
      int jcol = jg0 + wj * 64 + jt * 16 + lm;
      float bj = bias[jcol];
#pragma unroll
      for (int i = 0; i < 4; ++i)
#pragma unroll
        for (int r = 0; r < 4; ++r) {
          int m = m0 + wm * 64 + i * 16 + lq * 4 + r;
          outp[(size_t)m * C_ + jcol] = acc[i][jt][r] + bj;
        }
    }
  }
}

// ---------------- kv partials: kv[bh][d][e] = sum_n kf[bh][n][d]*v[bh][n][e]; z[bh][d] ----------------
__global__ __launch_bounds__(256) void kv_partial_k(
    const float* __restrict__ kf, const float* __restrict__ vv,
    float* __restrict__ kvp, float* __restrict__ zp) {
  const int bh = blockIdx.x, ch = blockIdx.y;
  const float* kfr = kf + ((size_t)bh * N_ + ch * CHROWS) * 64;
  const float* vr  = vv + ((size_t)bh * N_ + ch * CHROWS) * 64;
  __shared__ float ks[8][64], vs[8][64];
  const int tid = threadIdx.x;
  const int d0 = tid >> 2, eg = tid & 3;
  float acc[16] = {};
  float zacc = 0.f;
  for (int nb = 0; nb < CHROWS; nb += 8) {
    {
      int which = tid >> 7;
      int fl = tid & 127;
      int rr = fl >> 4, cc = (fl & 15) * 4;
      const float* src = which ? vr : kfr;
      float4 t4 = *(const float4*)&src[(size_t)(nb + rr) * 64 + cc];
      float* d = which ? &vs[rr][cc] : &ks[rr][cc];
      *(float4*)d = t4;
    }
    __syncthreads();
#pragma unroll
    for (int r = 0; r < 8; ++r) {
      float kd = ks[r][d0];
      if (eg == 0) zacc += kd;
#pragma unroll
      for (int i = 0; i < 16; ++i) acc[i] += kd * vs[r][eg * 16 + i];
    }
    __syncthreads();
  }
  size_t base = ((size_t)bh * NCH + ch) * 4096 + (size_t)d0 * 64 + eg * 16;
#pragma unroll
  for (int i = 0; i < 16; i += 4)
    *(float4*)&kvp[base + i] = make_float4(acc[i], acc[i+1], acc[i+2], acc[i+3]);
  if (eg == 0) zp[((size_t)bh * NCH + ch) * 64 + d0] = zacc;
}

__global__ __launch_bounds__(256) void kv_reduce_k(
    const float* __restrict__ kvp, const float* __restrict__ zp,
    float* __restrict__ kv, float* __restrict__ z) {
  const int bh = blockIdx.x, tid = threadIdx.x;
  for (int i = tid; i < 4096; i += 256) {
    float s = 0.f;
#pragma unroll
    for (int c = 0; c < NCH; ++c) s += kvp[((size_t)bh * NCH + c) * 4096 + i];
    kv[(size_t)bh * 4096 + i] = s;
  }
  if (tid < 64) {
    float s = 0.f;
#pragma unroll
    for (int c = 0; c < NCH; ++c) s += zp[((size_t)bh * NCH + c) * 64 + tid];
    z[bh * 64 + tid] = s;
  }
}

// ---------------- apply: Y[b,n,h*64+e] = (qf . kv) / max(qf . z, eps), bf16-split out ----------------
__global__ __launch_bounds__(256) void attn_apply_k(
    const float* __restrict__ qf, const float* __restrict__ kv,
    const float* __restrict__ z, short* __restrict__ Yh, short* __restrict__ Yl) {
  const int bh = blockIdx.x, nt = blockIdx.y;
  const int b = bh >> 4, hd = bh & 15;
  __shared__ float qs[128][65];
  __shared__ float kvs[64][68];
  __shared__ float zs[64];
  __shared__ float dens[128];
  const int tid = threadIdx.x;
  const float* qrow = qf + ((size_t)bh * N_ + nt * 128) * 64;
#pragma unroll
  for (int i = 0; i < 4; ++i) {
    int fl = tid + i * 256;
    int d = fl >> 4, cc = (fl & 15) * 4;
    float4 t4 = *(const float4*)&kv[(size_t)bh * 4096 + d * 64 + cc];
    kvs[d][cc] = t4.x; kvs[d][cc+1] = t4.y; kvs[d][cc+2] = t4.z; kvs[d][cc+3] = t4.w;
  }
  if (tid < 64) zs[tid] = z[bh * 64 + tid];
#pragma unroll
  for (int i = 0; i < 8; ++i) {
    int fl = tid + i * 256;
    int r = fl >> 4, cc = (fl & 15) * 4;
    float4 t4 = *(const float4*)&qrow[(size_t)r * 64 + cc];
    qs[r][cc] = t4.x; qs[r][cc+1] = t4.y; qs[r][cc+2] = t4.z; qs[r][cc+3] = t4.w;
  }
  __syncthreads();
  {
    int n = tid >> 1, half = tid & 1;
    float s = 0.f;
#pragma unroll
    for (int dd = 0; dd < 32; ++dd) {
      int d = half * 32 + dd;
      s += qs[n][d] * zs[d];
    }
    float other = __shfl_down(s, 1);
    if (half == 0) dens[n] = fmaxf(s + other, 1e-6f);
  }
  __syncthreads();
  const int ng = tid >> 3, eg = tid & 7;
  float acc[4][8] = {};
  for (int d = 0; d < 64; ++d) {
    float kvrow[8];
    *(float4*)&kvrow[0] = *(const float4*)&kvs[d][eg * 8];
    *(float4*)&kvrow[4] = *(const float4*)&kvs[d][eg * 8 + 4];
#pragma unroll
    for (int i = 0; i < 4; ++i) {
      float a = qs[ng * 4 + i][d];
#pragma unroll
      for (int j = 0; j < 8; ++j) acc[i][j] += a * kvrow[j];
    }
  }
#pragma unroll
  for (int i = 0; i < 4; ++i) {
    int nl = ng * 4 + i;
    int n = nt * 128 + nl;
    float inv = 1.0f / dens[nl];
    size_t off = ((size_t)b * N_ + n) * C_ + hd * 64 + eg * 8;
    short8 hv, lv;
#pragma unroll
    for (int j = 0; j < 8; ++j) {
      short hh, ll;
      split_bf16(acc[i][j] * inv, hh, ll);
      hv[j] = hh; lv[j] = ll;
    }
    *(short8*)&Yh[off] = hv;
    *(short8*)&Yl[off] = lv;
  }
}

extern "C" void kernel_launch(void* const* d_in, const int* in_sizes, int n_in,
                              void* d_out, int out_size, void* d_ws, size_t ws_size,
                              hipStream_t stream) {
  const float* x      = (const float*)d_in[0];
  const float* W_qkv  = (const float*)d_in[1];
  const float* b_qkv  = (const float*)d_in[2];
  const float* W_out  = (const float*)d_in[3];
  const float* b_out  = (const float*)d_in[4];
  const void*  mask   = d_in[5];
  float* out = (float*)d_out;

  const size_t bhnd = (size_t)B_ * H_ * N_ * D_;   // 16,777,216
  float* ws = (float*)d_ws;
  float* buf1 = ws;                    // kf, then qf
  float* buf2 = ws + bhnd;             // v, then Y hi/lo (bf16)
  short* Xh  = (short*)(ws + 2 * bhnd);
  short* Xl  = Xh + bhnd;
  float* tail = ws + 3 * bhnd;
  short* Wqh = (short*)tail;                       // 3072*1024 shorts
  short* Wql = Wqh + (size_t)3072 * 1024;
  short* Woh = Wql + (size_t)3072 * 1024;          // 1024*1024 shorts
  short* Wol = Woh + (size_t)1024 * 1024;
  float* tail2 = (float*)(Wol + (size_t)1024 * 1024);
  float* kvp = tail2;                              // 64*8*4096
  float* zp  = kvp + (size_t)64 * NCH * 4096;
  float* kv  = zp + (size_t)64 * NCH * 64;
  float* z   = kv + (size_t)64 * 4096;
  float* valid = z + 64 * 64;
  int*   flag  = (int*)(valid + M_);

  short* Yh = (short*)buf2;
  short* Yl = Yh + bhnd;

  mask_detect_k<<<1, 256, 0, stream>>>((const unsigned int*)mask, flag);
  mask_convert_k<<<M_ / 256, 256, 0, stream>>>(mask, flag, valid);
  split_f32_k<<<(int)(bhnd / 4 / 256), 256, 0, stream>>>(x, Xh, Xl, (int)(bhnd / 4));
  split_f32_k<<<3072 * 1024 / 4 / 256, 256, 0, stream>>>(W_qkv, Wqh, Wql, 3072 * 1024 / 4);
  split_f32_k<<<1024 * 1024 / 4 / 256, 256, 0, stream>>>(W_out, Woh, Wol, 1024 * 1024 / 4);
  // phase A: K and V projections (j in [1024,3072)) -> kf(buf1), v(buf2)
  gemm_split3_k<0><<<dim3(M_ / 128, 16), 256, 0, stream>>>(
      Xh, Xl, Wqh, Wql, b_qkv, valid, buf1, buf1, buf2, nullptr, 1024);
  kv_partial_k<<<dim3(B_ * H_, NCH), 256, 0, stream>>>(buf1, buf2, kvp, zp);
  kv_reduce_k<<<B_ * H_, 256, 0, stream>>>(kvp, zp, kv, z);
  // phase B: Q projection (j in [0,1024)) -> qf into buf1 (kf dead)
  gemm_split3_k<0><<<dim3(M_ / 128, 8), 256, 0, stream>>>(
      Xh, Xl, Wqh, Wql, b_qkv, valid, buf1, buf1, buf2, nullptr, 0);
  // apply: reads qf(buf1), writes Y hi/lo into buf2 (v dead)
  attn_apply_k<<<dim3(B_ * H_, N_ / 128), 256, 0, stream>>>(buf1, kv, z, Yh, Yl);
  // out-proj
  gemm_split3_k<1><<<dim3(M_ / 128, 8), 256, 0, stream>>>(
      Yh, Yl, Woh, Wol, b_out, valid, nullptr, nullptr, nullptr, out, 0);
}

// Round 4
// 623.577 us; speedup vs baseline: 2.7829x; 1.1937x over previous
//
#include <hip/hip_runtime.h>
#include <math.h>

#define B_ 4
#define N_ 4096
#define C_ 1024
#define H_ 16
#define D_ 64
#define M_ (B_*N_)      // 16384 rows
#define GK 1024         // GEMM K dim (both GEMMs)
#define NCH 8           // N-chunks for kv partial reduction
#define CHROWS (N_/NCH) // 512

typedef __attribute__((ext_vector_type(8))) _Float16 f16x8;
typedef __attribute__((ext_vector_type(4))) _Float16 f16x4;
typedef __attribute__((ext_vector_type(4))) float f32x4;

__device__ __forceinline__ float phi_f(float t) {
  return (t > 0.0f) ? (t + 1.0f) : __expf(t);
}

#define GLOAD(gp, lp) __builtin_amdgcn_global_load_lds( \
    (const __attribute__((address_space(1))) unsigned int*)(gp), \
    (__attribute__((address_space(3))) unsigned int*)(lp), 16, 0, 0)

__device__ __forceinline__ f32x4 mfma16h(f16x8 a, f16x8 b, f32x4 c) {
  return __builtin_amdgcn_mfma_f32_16x16x32_f16(a, b, c, 0, 0, 0);
}

// ---------------- mask dtype detection ----------------
__global__ __launch_bounds__(256) void mask_detect_k(const unsigned int* __restrict__ w,
                                                     int* __restrict__ flag) {
  __shared__ int notint, notflt;
  if (threadIdx.x == 0) { notint = 0; notflt = 0; }
  __syncthreads();
  int ni = 0, nf = 0;
  for (int i = threadIdx.x; i < 4096; i += 256) {
    unsigned int v = w[i];
    if (v > 1u) ni = 1;
    if (v != 0u && v != 0x3F800000u) nf = 1;
  }
  if (ni) atomicOr(&notint, 1);
  if (nf) atomicOr(&notflt, 1);
  __syncthreads();
  if (threadIdx.x == 0) *flag = (!notint) ? 0 : ((!notflt) ? 1 : 2);
}

__global__ __launch_bounds__(256) void mask_convert_k(const void* __restrict__ mask,
                                                      const int* __restrict__ flag,
                                                      float* __restrict__ valid) {
  int i = blockIdx.x * 256 + threadIdx.x;  // 16384 total
  int f = *flag;
  int m;
  if (f == 0)      m = ((const int*)mask)[i] != 0;
  else if (f == 1) m = ((const float*)mask)[i] != 0.0f;
  else             m = ((const unsigned char*)mask)[i] != 0;
  valid[i] = m ? 0.0f : 1.0f;  // True = PAD -> 0
}

// ---------------- fp32 -> fp16 single convert (x4) ----------------
__global__ __launch_bounds__(256) void conv_f16_k(const float* __restrict__ src,
                                                  _Float16* __restrict__ dst, int n4) {
  int i = blockIdx.x * 256 + threadIdx.x;
  if (i >= n4) return;
  float4 v = ((const float4*)src)[i];
  f16x4 h;
  h[0] = (_Float16)v.x; h[1] = (_Float16)v.y;
  h[2] = (_Float16)v.z; h[3] = (_Float16)v.w;
  ((f16x4*)dst)[i] = h;
}

// ---------------- fp32 -> fp16 hi/lo split (x4) ----------------
__global__ __launch_bounds__(256) void split_f16_k(const float* __restrict__ src,
                                                   _Float16* __restrict__ h,
                                                   _Float16* __restrict__ l, int n4) {
  int i = blockIdx.x * 256 + threadIdx.x;
  if (i >= n4) return;
  float4 v = ((const float4*)src)[i];
  f16x4 hv, lv;
  float vs[4] = {v.x, v.y, v.z, v.w};
#pragma unroll
  for (int q = 0; q < 4; ++q) {
    _Float16 hh = (_Float16)vs[q];
    _Float16 ll = (_Float16)(vs[q] - (float)hh);
    hv[q] = hh; lv[q] = ll;
  }
  ((f16x4*)h)[i] = hv;
  ((f16x4*)l)[i] = lv;
}

// ---------------- 2-term fp16 MFMA GEMM: out[m][j] = sum_k A[m][k]*B[j][k] ----------------
// A single fp16, B split-2 fp16 (hi+lo).  128x128 tile, BK=32, 4 waves (2x2),
// per-wave 4x4 of 16x16x32 MFMA x 2 terms.  LDS in fragment order (see r3).
// EPI 0: qkv epilogue (bias + phi/mask -> [B,H,N,D] fp32); EPI 1: bias + row-major fp32.
template <int EPI>
__global__ __launch_bounds__(256) void gemm_f16_k(
    const _Float16* __restrict__ A,
    const _Float16* __restrict__ Bh, const _Float16* __restrict__ Bl,
    const float* __restrict__ bias, const float* __restrict__ valid,
    float* __restrict__ qf, float* __restrict__ kf, float* __restrict__ vv,
    float* __restrict__ outp, int jb) {
  __shared__ _Float16 lA[4096], lBh[4096], lBl[4096];  // 8KB each
  const int tid = threadIdx.x;
  const int lane = tid & 63, w = tid >> 6;
  const int lm = lane & 15, lq = lane >> 4;
  const int wm = w >> 1, wj = w & 1;
  const int m0 = blockIdx.x * 128;
  const int jg0 = jb + blockIdx.y * 128;
  const int colk = lq * 8;
  const size_t rA0 = (size_t)(m0 + w * 16 + lm) * GK + colk;
  const size_t rA1 = rA0 + (size_t)64 * GK;
  const size_t rB0 = (size_t)(jg0 + w * 16 + lm) * GK + colk;
  const size_t rB1 = rB0 + (size_t)64 * GK;
  _Float16* dA0 = lA  + w * 512;  _Float16* dA1 = lA  + (w + 4) * 512;
  _Float16* dB0 = lBh + w * 512;  _Float16* dB1 = lBh + (w + 4) * 512;
  _Float16* eB0 = lBl + w * 512;  _Float16* eB1 = lBl + (w + 4) * 512;

  f32x4 acc[4][4] = {};
  for (int k0 = 0; k0 < GK; k0 += 32) {
    GLOAD(A + rA0 + k0, dA0);
    GLOAD(A + rA1 + k0, dA1);
    GLOAD(Bh + rB0 + k0, dB0);
    GLOAD(Bh + rB1 + k0, dB1);
    GLOAD(Bl + rB0 + k0, eB0);
    GLOAD(Bl + rB1 + k0, eB1);
    __syncthreads();
    f16x8 a[4], b_h[4], b_l[4];
#pragma unroll
    for (int i = 0; i < 4; ++i) {
      a[i]   = *(const f16x8*)&lA [(wm * 4 + i) * 512 + lane * 8];
      b_h[i] = *(const f16x8*)&lBh[(wj * 4 + i) * 512 + lane * 8];
      b_l[i] = *(const f16x8*)&lBl[(wj * 4 + i) * 512 + lane * 8];
    }
#pragma unroll
    for (int i = 0; i < 4; ++i)
#pragma unroll
      for (int j = 0; j < 4; ++j) {
        acc[i][j] = mfma16h(a[i], b_h[j], acc[i][j]);
        acc[i][j] = mfma16h(a[i], b_l[j], acc[i][j]);
      }
    __syncthreads();
  }

  // C/D layout: col = lane&15, row = (lane>>4)*4 + reg   [m89-verified]
  if (EPI == 0) {
    const int t = jg0 >> 10;  // 0:q 1:k 2:v  (uniform per block: 128 | 1024)
    float* dst = (t == 0) ? qf : ((t == 1) ? kf : vv);
    float vld[4][4];
#pragma unroll
    for (int i = 0; i < 4; ++i)
#pragma unroll
      for (int r = 0; r < 4; ++r)
        vld[i][r] = (t == 0) ? 1.0f : valid[m0 + wm * 64 + i * 16 + lq * 4 + r];
#pragma unroll
    for (int jt = 0; jt < 4; ++jt) {
      int jcol = jg0 + wj * 64 + jt * 16 + lm;
      float bj = bias[jcol];
      int c = jcol & 1023, hd = c >> 6, d = c & 63;
#pragma unroll
      for (int i = 0; i < 4; ++i)
#pragma unroll
        for (int r = 0; r < 4; ++r) {
          int m = m0 + wm * 64 + i * 16 + lq * 4 + r;
          int b = m >> 12, n = m & 4095;
          float val = acc[i][jt][r] + bj;
          if (t <= 1) val = phi_f(val);
          if (t >= 1) val *= vld[i][r];
          dst[(((size_t)(b * H_ + hd) * N_ + n) << 6) + d] = val;
        }
    }
  } else {
#pragma unroll
    for (int jt = 0; jt < 4; ++jt) {
      int jcol = jg0 + wj * 64 + jt * 16 + lm;
      float bj = bias[jcol];
#pragma unroll
      for (int i = 0; i < 4; ++i)
#pragma unroll
        for (int r = 0; r < 4; ++r) {
          int m = m0 + wm * 64 + i * 16 + lq * 4 + r;
          outp[(size_t)m * C_ + jcol] = acc[i][jt][r] + bj;
        }
    }
  }
}

// ---------------- kv partials: kv[bh][d][e] = sum_n kf[bh][n][d]*v[bh][n][e]; z[bh][d] ----------------
__global__ __launch_bounds__(256) void kv_partial_k(
    const float* __restrict__ kf, const float* __restrict__ vv,
    float* __restrict__ kvp, float* __restrict__ zp) {
  const int bh = blockIdx.x, ch = blockIdx.y;
  const float* kfr = kf + ((size_t)bh * N_ + ch * CHROWS) * 64;
  const float* vr  = vv + ((size_t)bh * N_ + ch * CHROWS) * 64;
  __shared__ float ks[8][64], vs[8][64];
  const int tid = threadIdx.x;
  const int d0 = tid >> 2, eg = tid & 3;
  float acc[16] = {};
  float zacc = 0.f;
  for (int nb = 0; nb < CHROWS; nb += 8) {
    {
      int which = tid >> 7;
      int fl = tid & 127;
      int rr = fl >> 4, cc = (fl & 15) * 4;
      const float* src = which ? vr : kfr;
      float4 t4 = *(const float4*)&src[(size_t)(nb + rr) * 64 + cc];
      float* d = which ? &vs[rr][cc] : &ks[rr][cc];
      *(float4*)d = t4;
    }
    __syncthreads();
#pragma unroll
    for (int r = 0; r < 8; ++r) {
      float kd = ks[r][d0];
      if (eg == 0) zacc += kd;
#pragma unroll
      for (int i = 0; i < 16; ++i) acc[i] += kd * vs[r][eg * 16 + i];
    }
    __syncthreads();
  }
  size_t base = ((size_t)bh * NCH + ch) * 4096 + (size_t)d0 * 64 + eg * 16;
#pragma unroll
  for (int i = 0; i < 16; i += 4)
    *(float4*)&kvp[base + i] = make_float4(acc[i], acc[i+1], acc[i+2], acc[i+3]);
  if (eg == 0) zp[((size_t)bh * NCH + ch) * 64 + d0] = zacc;
}

__global__ __launch_bounds__(256) void kv_reduce_k(
    const float* __restrict__ kvp, const float* __restrict__ zp,
    float* __restrict__ kv, float* __restrict__ z) {
  const int bh = blockIdx.x, tid = threadIdx.x;
  for (int i = tid; i < 4096; i += 256) {
    float s = 0.f;
#pragma unroll
    for (int c = 0; c < NCH; ++c) s += kvp[((size_t)bh * NCH + c) * 4096 + i];
    kv[(size_t)bh * 4096 + i] = s;
  }
  if (tid < 64) {
    float s = 0.f;
#pragma unroll
    for (int c = 0; c < NCH; ++c) s += zp[((size_t)bh * NCH + c) * 64 + tid];
    z[bh * 64 + tid] = s;
  }
}

// ---------------- apply: Y[b,n,h*64+e] = (qf . kv) / max(qf . z, eps), fp16 out ----------------
__global__ __launch_bounds__(256) void attn_apply_k(
    const float* __restrict__ qf, const float* __restrict__ kv,
    const float* __restrict__ z, _Float16* __restrict__ Y) {
  const int bh = blockIdx.x, nt = blockIdx.y;
  const int b = bh >> 4, hd = bh & 15;
  __shared__ float qs[128][65];
  __shared__ float kvs[64][68];
  __shared__ float zs[64];
  __shared__ float dens[128];
  const int tid = threadIdx.x;
  const float* qrow = qf + ((size_t)bh * N_ + nt * 128) * 64;
#pragma unroll
  for (int i = 0; i < 4; ++i) {
    int fl = tid + i * 256;
    int d = fl >> 4, cc = (fl & 15) * 4;
    float4 t4 = *(const float4*)&kv[(size_t)bh * 4096 + d * 64 + cc];
    kvs[d][cc] = t4.x; kvs[d][cc+1] = t4.y; kvs[d][cc+2] = t4.z; kvs[d][cc+3] = t4.w;
  }
  if (tid < 64) zs[tid] = z[bh * 64 + tid];
#pragma unroll
  for (int i = 0; i < 8; ++i) {
    int fl = tid + i * 256;
    int r = fl >> 4, cc = (fl & 15) * 4;
    float4 t4 = *(const float4*)&qrow[(size_t)r * 64 + cc];
    qs[r][cc] = t4.x; qs[r][cc+1] = t4.y; qs[r][cc+2] = t4.z; qs[r][cc+3] = t4.w;
  }
  __syncthreads();
  {
    int n = tid >> 1, half = tid & 1;
    float s = 0.f;
#pragma unroll
    for (int dd = 0; dd < 32; ++dd) {
      int d = half * 32 + dd;
      s += qs[n][d] * zs[d];
    }
    float other = __shfl_down(s, 1);
    if (half == 0) dens[n] = fmaxf(s + other, 1e-6f);
  }
  __syncthreads();
  const int ng = tid >> 3, eg = tid & 7;
  float acc[4][8] = {};
  for (int d = 0; d < 64; ++d) {
    float kvrow[8];
    *(float4*)&kvrow[0] = *(const float4*)&kvs[d][eg * 8];
    *(float4*)&kvrow[4] = *(const float4*)&kvs[d][eg * 8 + 4];
#pragma unroll
    for (int i = 0; i < 4; ++i) {
      float a = qs[ng * 4 + i][d];
#pragma unroll
      for (int j = 0; j < 8; ++j) acc[i][j] += a * kvrow[j];
    }
  }
#pragma unroll
  for (int i = 0; i < 4; ++i) {
    int nl = ng * 4 + i;
    int n = nt * 128 + nl;
    float inv = 1.0f / dens[nl];
    size_t off = ((size_t)b * N_ + n) * C_ + hd * 64 + eg * 8;
    f16x8 hv;
#pragma unroll
    for (int j = 0; j < 8; ++j) hv[j] = (_Float16)(acc[i][j] * inv);
    *(f16x8*)&Y[off] = hv;
  }
}

extern "C" void kernel_launch(void* const* d_in, const int* in_sizes, int n_in,
                              void* d_out, int out_size, void* d_ws, size_t ws_size,
                              hipStream_t stream) {
  const float* x      = (const float*)d_in[0];
  const float* W_qkv  = (const float*)d_in[1];
  const float* b_qkv  = (const float*)d_in[2];
  const float* W_out  = (const float*)d_in[3];
  const float* b_out  = (const float*)d_in[4];
  const void*  mask   = d_in[5];
  float* out = (float*)d_out;

  const size_t bhnd = (size_t)B_ * H_ * N_ * D_;   // 16,777,216
  float* ws = (float*)d_ws;
  float* buf1 = ws;                    // kf, then qf (fp32)
  float* buf2 = ws + bhnd;             // v (fp32), then Y (fp16)
  _Float16* Xh  = (_Float16*)(ws + 2 * bhnd);      // bhnd halfs
  _Float16* Wqh = Xh + bhnd;                       // 3072*1024
  _Float16* Wql = Wqh + (size_t)3072 * 1024;
  _Float16* Woh = Wql + (size_t)3072 * 1024;       // 1024*1024
  _Float16* Wol = Woh + (size_t)1024 * 1024;
  float* tail2 = (float*)(Wol + (size_t)1024 * 1024);
  float* kvp = tail2;                              // 64*8*4096
  float* zp  = kvp + (size_t)64 * NCH * 4096;
  float* kv  = zp + (size_t)64 * NCH * 64;
  float* z   = kv + (size_t)64 * 4096;
  float* valid = z + 64 * 64;
  int*   flag  = (int*)(valid + M_);

  _Float16* Y = (_Float16*)buf2;

  mask_detect_k<<<1, 256, 0, stream>>>((const unsigned int*)mask, flag);
  mask_convert_k<<<M_ / 256, 256, 0, stream>>>(mask, flag, valid);
  conv_f16_k<<<(int)(bhnd / 4 / 256), 256, 0, stream>>>(x, Xh, (int)(bhnd / 4));
  split_f16_k<<<3072 * 1024 / 4 / 256, 256, 0, stream>>>(W_qkv, Wqh, Wql, 3072 * 1024 / 4);
  split_f16_k<<<1024 * 1024 / 4 / 256, 256, 0, stream>>>(W_out, Woh, Wol, 1024 * 1024 / 4);
  // phase A: K and V projections (j in [1024,3072)) -> kf(buf1), v(buf2)
  gemm_f16_k<0><<<dim3(M_ / 128, 16), 256, 0, stream>>>(
      Xh, Wqh, Wql, b_qkv, valid, buf1, buf1, buf2, nullptr, 1024);
  kv_partial_k<<<dim3(B_ * H_, NCH), 256, 0, stream>>>(buf1, buf2, kvp, zp);
  kv_reduce_k<<<B_ * H_, 256, 0, stream>>>(kvp, zp, kv, z);
  // phase B: Q projection (j in [0,1024)) -> qf into buf1 (kf dead)
  gemm_f16_k<0><<<dim3(M_ / 128, 8), 256, 0, stream>>>(
      Xh, Wqh, Wql, b_qkv, valid, buf1, buf1, buf2, nullptr, 0);
  // apply: reads qf(buf1), writes Y (fp16) into buf2 (v dead)
  attn_apply_k<<<dim3(B_ * H_, N_ / 128), 256, 0, stream>>>(buf1, kv, z, Y);
  // out-proj: A = Y (fp16 single), B = W_out split-2
  gemm_f16_k<1><<<dim3(M_ / 128, 8), 256, 0, stream>>>(
      Y, Woh, Wol, b_out, valid, nullptr, nullptr, nullptr, out, 0);
}